// Round 5
// baseline (1893.540 us; speedup 1.0000x reference)
//
#include <hip/hip_runtime.h>

typedef __attribute__((ext_vector_type(8))) short short8;
typedef __attribute__((ext_vector_type(4))) float f32x4;

#define LOG2E 1.4426950408889634f

__device__ __forceinline__ unsigned short f2bf(float f){
  unsigned u = __float_as_uint(f);
  unsigned r = u + 0x7fffu + ((u >> 16) & 1u);   // round-to-nearest-even
  return (unsigned short)(r >> 16);
}

__device__ __forceinline__ float tanh_fast(float x){
  float ax = fabsf(x);
  float e = __builtin_amdgcn_exp2f(ax * (2.0f * LOG2E));       // e^(2|x|)
  float r = 1.0f - 2.0f * __builtin_amdgcn_rcpf(e + 1.0f);     // |x| big -> e=inf -> r=1
  return copysignf(r, x);
}

__device__ __forceinline__ void gload16(const unsigned short* g, unsigned short* l){
  __builtin_amdgcn_global_load_lds((const __attribute__((address_space(1))) unsigned int*)g,
                                   (__attribute__((address_space(3))) unsigned int*)l,
                                   16, 0, 0);
}

// ---------------- prep kernels ----------------

// X[row][0:512] = bf16(embedding[x[b][t]][:]), row = b*256+t
__global__ void k_gather_x(const int* __restrict__ x, const float* __restrict__ emb,
                           unsigned short* __restrict__ X)
{
  int row = blockIdx.x;
  int b = row >> 8, t = row & 255;
  int tok = x[b * 257 + t];
  const float* e = emb + (size_t)tok * 512;
  unsigned short* o = X + (size_t)row * 512;
  for (int i = threadIdx.x; i < 512; i += blockDim.x) o[i] = f2bf(e[i]);
}

// h_buf[b][0][:] = bf16(initial_state)  (state "after step -1")
__global__ void k_init_h0(const float* __restrict__ init, unsigned short* __restrict__ hbuf){
  int i = blockIdx.x * 256 + threadIdx.x;   // 16*1024
  int b = i >> 10, u = i & 1023;
  hbuf[(size_t)(b * 257) * 1024 + u] = f2bf(init[u]);
}

// dst(C,R) bf16 = transpose(src(R,C) f32); R,C multiples of 64
__global__ __launch_bounds__(256) void k_transpose(
    const float* __restrict__ src, unsigned short* __restrict__ dst, int R, int C)
{
  __shared__ float tile[64][65];
  int c0 = blockIdx.x << 6, r0 = blockIdx.y << 6;
  int tid = threadIdx.x;
  for (int i = 0; i < 16; i++){
    int e = (i << 8) + tid; int r = e >> 6, c = e & 63;
    tile[r][c] = src[(size_t)(r0 + r) * C + c0 + c];
  }
  __syncthreads();
  for (int i = 0; i < 16; i++){
    int e = (i << 8) + tid; int rr = e >> 6, cc = e & 63;
    dst[(size_t)(c0 + rr) * R + r0 + cc] = f2bf(tile[cc][rr]);
  }
}

// guard fallback: deterministic, touches only out[0]
__global__ void k_guard(float* __restrict__ out){ if (threadIdx.x == 0) out[0] = 0.f; }

// ---------------- generic 128x128 bf16 MFMA GEMM (m97-style) ----------------
// mode 0 (ZI):  C[m*1024+n]   = A(X,512-stride) @ B(Wit)  + b0[n]+b1[n]
// mode 1 (PRE): C[Zrow*1024 + 256J + n] += h_buf-rows @ B(Wt block-J rows)
// mode 2 (D):   C[m*32000+n]  = h_buf-rows @ B(Wot)
__global__ __launch_bounds__(256) void k_gemm(
    const unsigned short* __restrict__ A, const unsigned short* __restrict__ B,
    float* __restrict__ C, const float* __restrict__ b0, const float* __restrict__ b1,
    int K, int nTiles, int mode, int J, int ldb)
{
  __shared__ unsigned short aT[128 * 32];
  __shared__ unsigned short bT[128 * 32];
  int bid = blockIdx.x;
  int mt = bid / nTiles, nt = bid % nTiles;
  int m0 = mt << 7, n0 = nt << 7;
  int tid = threadIdx.x;
  int lane = tid & 63, wave = tid >> 6;
  int wm = wave >> 1, wn = wave & 1;
  int wbase = tid & ~63;

  // staging addresses: chunk e = i*256+tid covers LDS bytes e*16 -> row e>>2, k-chunk (e&3)*8
  const unsigned short* arow[2];
  int kc[2];
  for (int i = 0; i < 2; i++){
    int e = (i << 8) + tid;
    int r = m0 + (e >> 2);
    kc[i] = (e & 3) << 3;
    const unsigned short* p;
    if (mode == 0)      p = A + (size_t)r * 512;
    else if (mode == 1){ int nA = 256 >> J; int bb = r >> (8 - J); int a = r & (nA - 1);
                         p = A + (size_t)(bb * 257 + (a << J)) * 1024; }
    else               { int bb = r >> 8; int t = r & 255;
                         p = A + (size_t)(bb * 257 + t + 1) * 1024; }
    arow[i] = p;
  }
  const unsigned short* brow[2];
  for (int i = 0; i < 2; i++){
    int e = (i << 8) + tid;
    brow[i] = B + (size_t)(n0 + (e >> 2)) * ldb + ((e & 3) << 3);
  }

  f32x4 acc[4][4] = {};

  int kT = K >> 5;
  for (int kt = 0; kt < kT; kt++){
    int k0 = kt << 5;
    __syncthreads();
    for (int i = 0; i < 2; i++)
      gload16(arow[i] + k0 + kc[i], &aT[((i << 8) + wbase) << 3]);
    for (int i = 0; i < 2; i++)
      gload16(brow[i] + k0, &bT[((i << 8) + wbase) << 3]);
    __syncthreads();
    short8 af[4], bf[4];
#pragma unroll
    for (int i = 0; i < 4; i++)
      af[i] = *(const short8*)&aT[((wm << 6) + (i << 4) + (lane & 15)) * 32 + ((lane >> 4) << 3)];
#pragma unroll
    for (int j = 0; j < 4; j++)
      bf[j] = *(const short8*)&bT[((wn << 6) + (j << 4) + (lane & 15)) * 32 + ((lane >> 4) << 3)];
#pragma unroll
    for (int i = 0; i < 4; i++)
#pragma unroll
      for (int j = 0; j < 4; j++)
        acc[i][j] = __builtin_amdgcn_mfma_f32_16x16x32_bf16(af[i], bf[j], acc[i][j], 0, 0, 0);
  }

#pragma unroll
  for (int i = 0; i < 4; i++)
#pragma unroll
    for (int j = 0; j < 4; j++)
#pragma unroll
      for (int r = 0; r < 4; r++){
        int mg = m0 + (wm << 6) + (i << 4) + ((lane >> 4) << 2) + r;
        int ng = n0 + (wn << 6) + (j << 4) + (lane & 15);
        float v = acc[i][j][r];
        if (mode == 0){
          C[(size_t)mg * 1024 + ng] = v + b0[ng] + b1[ng];
        } else if (mode == 1){
          int nA = 256 >> J; int bb = mg >> (8 - J); int a = mg & (nA - 1);
          C[(size_t)(bb * 256 + (a << J)) * 1024 + (J << 8) + ng] += v;
        } else {
          C[(size_t)mg * 32000 + ng] = v;
        }
      }
}

// ---------------- sequential self-recurrent chain for clock-block J ----------------
// one workgroup, 512 threads (8 waves); W_JJ^T held in registers (16 frags/lane);
// h (16 batches x 256 units, bf16) in LDS; per active step:
//   h = tanh(Z[t] (incl. lower-block contrib) + h_prev @ W_JJ)
// then broadcast h into h_buf rows t+1 .. t+p.
__global__ __launch_bounds__(512) void k_chain(
    const float* __restrict__ Z, unsigned short* __restrict__ hbuf,
    const unsigned short* __restrict__ Wt, const float* __restrict__ init, int J)
{
  __shared__ unsigned short h[16][264];   // +8 pad: conflict-free b128 frag reads
  const int p = 1 << J;
  int tid = threadIdx.x, lane = tid & 63, wave = tid >> 6;

  for (int i = tid; i < 4096; i += 512){
    int b = i >> 8, c = i & 255;
    h[b][c] = f2bf(init[(J << 8) + c]);
  }

  short8 wf[2][8];   // B frags: B[k][n] = Wt[256J+n][256J+k]
#pragma unroll
  for (int nt = 0; nt < 2; nt++){
    int ncol = (wave << 5) + (nt << 4) + (lane & 15);
    const unsigned short* wr = Wt + (size_t)((J << 8) + ncol) * 1024 + (J << 8) + ((lane >> 4) << 3);
#pragma unroll
    for (int ks = 0; ks < 8; ks++)
      wf[nt][ks] = *(const short8*)(wr + (ks << 5));
  }
  __syncthreads();

  for (int t = 0; t < 256; t += p){
    short8 af[8];
#pragma unroll
    for (int ks = 0; ks < 8; ks++)
      af[ks] = *(const short8*)&h[lane & 15][(ks << 5) + ((lane >> 4) << 3)];

    float zv[2][4];                 // prefetch Z early (hides L2 latency under MFMA)
#pragma unroll
    for (int nt = 0; nt < 2; nt++)
#pragma unroll
      for (int r = 0; r < 4; r++){
        int b = ((lane >> 4) << 2) + r;
        int c = (wave << 5) + (nt << 4) + (lane & 15);
        zv[nt][r] = Z[(size_t)((b << 8) + t) * 1024 + (J << 8) + c];
      }

    f32x4 acc[2] = {};
#pragma unroll
    for (int nt = 0; nt < 2; nt++)
#pragma unroll
      for (int ks = 0; ks < 8; ks++)
        acc[nt] = __builtin_amdgcn_mfma_f32_16x16x32_bf16(af[ks], wf[nt][ks], acc[nt], 0, 0, 0);

    __syncthreads();                // all waves done reading h
#pragma unroll
    for (int nt = 0; nt < 2; nt++)
#pragma unroll
      for (int r = 0; r < 4; r++){
        int b = ((lane >> 4) << 2) + r;
        int c = (wave << 5) + (nt << 4) + (lane & 15);
        h[b][c] = f2bf(tanh_fast(acc[nt][r] + zv[nt][r]));
      }
    __syncthreads();                // h complete before reads/copy

    for (int q = 0; q < p; q++){    // broadcast held state
      int ti = t + q + 1;
#pragma unroll
      for (int i = 0; i < 4; i++){
        int d = tid + (i << 9);     // 0..2047 dwords (16 rows * 128)
        int b = d >> 7, cp = d & 127;
        *(unsigned int*)(hbuf + (size_t)(b * 257 + ti) * 1024 + (J << 8) + (cp << 1)) =
            *(const unsigned int*)&h[b][cp << 1];
      }
    }
  }
}

// ---------------- loss: one-pass online logsumexp per row + masked target gather ----------------
__global__ __launch_bounds__(256) void k_loss_rows(
    const float* __restrict__ L, const int* __restrict__ x,
    const int* __restrict__ xsl, float* __restrict__ lacc)
{
  int row = blockIdx.x;             // b*256+t
  int b = row >> 8, t = row & 255;
  const float* Lr = L + (size_t)row * 32000;
  int tid = threadIdx.x, lane = tid & 63, wave = tid >> 6;
  float m = -3.0e38f, s = 0.f;
  for (int i = tid; i < 32000; i += 256){
    float v = Lr[i];
    float mn = fmaxf(m, v);
    s = s * __builtin_amdgcn_exp2f((m - mn) * LOG2E) + __builtin_amdgcn_exp2f((v - mn) * LOG2E);
    m = mn;
  }
  __shared__ float smax[4], ssum[4];
  float wm_ = m;
  for (int off = 32; off >= 1; off >>= 1) wm_ = fmaxf(wm_, __shfl_xor(wm_, off));
  if (lane == 0) smax[wave] = wm_;
  __syncthreads();
  float M = fmaxf(fmaxf(smax[0], smax[1]), fmaxf(smax[2], smax[3]));
  float sc = s * __builtin_amdgcn_exp2f((m - M) * LOG2E);
  for (int off = 32; off >= 1; off >>= 1) sc += __shfl_xor(sc, off);
  if (lane == 0) ssum[wave] = sc;
  __syncthreads();
  if (tid == 0){
    float S = ssum[0] + ssum[1] + ssum[2] + ssum[3];
    float lse = M + __builtin_amdgcn_logf(S) * 0.6931471805599453f;
    int y = x[b * 257 + t + 1];
    if (t < xsl[b] - 1) atomicAdd(lacc, Lr[y] - lse);
  }
}

__global__ void k_final(const float* __restrict__ lacc, const int* __restrict__ xsl,
                        float* __restrict__ out){
  if (threadIdx.x == 0){
    int ss = 0;
    for (int b = 0; b < 16; b++) ss += xsl[b] - 1;
    out[0] = -lacc[0] / (float)ss;
  }
}

// ---------------- launch ----------------
extern "C" void kernel_launch(void* const* d_in, const int* in_sizes, int n_in,
                              void* d_out, int out_size, void* d_ws, size_t ws_size,
                              hipStream_t stream)
{
  const int*   x   = (const int*)d_in[0];
  const int*   xsl = (const int*)d_in[1];
  const float* Wi  = (const float*)d_in[2];
  const float* Wh  = (const float*)d_in[3];
  const float* Wo  = (const float*)d_in[4];
  const float* bi  = (const float*)d_in[5];
  const float* bh  = (const float*)d_in[6];
  const float* ini = (const float*)d_in[7];
  const float* emb = (const float*)d_in[8];
  float* out = (float*)d_out;

  // workspace layout (bytes)
  const size_t WS_NEED = 98074628;
  if (ws_size < WS_NEED){           // refuse to scribble OOB: clean fail, not a crash
    k_guard<<<1, 64, 0, stream>>>(out);
    return;
  }

  char* ws = (char*)d_ws;
  float*          Z    = (float*)(ws + 0);                   // 4096*1024 f32   = 16777216
  unsigned short* hbuf = (unsigned short*)(ws + 16777216);   // 16*257*1024 bf16 = 8421376
  unsigned short* Wt   = (unsigned short*)(ws + 25198592);   // 1024*1024 bf16   = 2097152
  unsigned short* Wit  = (unsigned short*)(ws + 27295744);   // 1024*512 bf16    = 1048576
  unsigned short* X    = (unsigned short*)(ws + 28344320);   // 4096*512 bf16    = 4194304
  unsigned short* Wot  = (unsigned short*)(ws + 32538624);   // 32000*1024 bf16  = 65536000
  float*          lacc = (float*)(ws + 98074624);

  hipMemsetAsync(lacc, 0, 4, stream);

  k_gather_x<<<4096, 128, 0, stream>>>(x, emb, X);
  k_init_h0<<<64, 256, 0, stream>>>(ini, hbuf);
  k_transpose<<<dim3(1024 / 64, 512 / 64), 256, 0, stream>>>(Wi, Wit, 512, 1024);
  k_transpose<<<dim3(1024 / 64, 1024 / 64), 256, 0, stream>>>(Wh, Wt, 1024, 1024);
  k_transpose<<<dim3(32000 / 64, 1024 / 64), 256, 0, stream>>>(Wo, Wot, 1024, 32000);

  // Z = X @ Wi^T + (bi+bh)   : M=4096 N=1024 K=512
  k_gemm<<<(4096 / 128) * (1024 / 128), 256, 0, stream>>>(X, Wit, Z, bi, bh, 512, 8, 0, 0, 512);

  // clockwork phases
  k_chain<<<1, 512, 0, stream>>>(Z, hbuf, Wt, ini, 0);
  for (int j = 1; j <= 3; j++){
    int nA = 256 >> j;
    int grid = ((16 * nA) / 128) * 2;    // M/128 * N-tiles(2)
    k_gemm<<<grid, 256, 0, stream>>>(hbuf, Wt + (size_t)(256 * j) * 1024, Z,
                                     nullptr, nullptr, 256 * j, 2, 1, j, 1024);
    k_chain<<<1, 512, 0, stream>>>(Z, hbuf, Wt, ini, j);
  }

  // logits = h @ Wo : M=4096 N=32000 K=1024  -> d_out+1
  k_gemm<<<(4096 / 128) * (32000 / 128), 256, 0, stream>>>(hbuf, Wot, out + 1,
                                   nullptr, nullptr, 1024, 250, 2, 0, 1024);

  k_loss_rows<<<4096, 256, 0, stream>>>(out + 1, x, xsl, lacc);
  k_final<<<1, 64, 0, stream>>>(lacc, xsl, out);
}

// Round 7
// 1771.525 us; speedup vs baseline: 1.0689x; 1.0689x over previous
//
#include <hip/hip_runtime.h>

typedef __attribute__((ext_vector_type(8))) short short8;
typedef __attribute__((ext_vector_type(4))) float f32x4;

#define LOG2E 1.4426950408889634f

__device__ __forceinline__ unsigned short f2bf(float f){
  unsigned u = __float_as_uint(f);
  unsigned r = u + 0x7fffu + ((u >> 16) & 1u);   // round-to-nearest-even
  return (unsigned short)(r >> 16);
}

__device__ __forceinline__ float tanh_fast(float x){
  float ax = fabsf(x);
  float e = __builtin_amdgcn_exp2f(ax * (2.0f * LOG2E));       // e^(2|x|)
  float r = 1.0f - 2.0f * __builtin_amdgcn_rcpf(e + 1.0f);     // |x| big -> e=inf -> r=1
  return copysignf(r, x);
}

__device__ __forceinline__ void gload16(const unsigned short* g, unsigned short* l){
  __builtin_amdgcn_global_load_lds((const __attribute__((address_space(1))) unsigned int*)g,
                                   (__attribute__((address_space(3))) unsigned int*)l,
                                   16, 0, 0);
}

// ---------------- prep kernels ----------------

// X[row][0:512] = bf16(embedding[x[b][t]][:]), row = b*256+t
__global__ void k_gather_x(const int* __restrict__ x, const float* __restrict__ emb,
                           unsigned short* __restrict__ X)
{
  int row = blockIdx.x;
  int b = row >> 8, t = row & 255;
  int tok = x[b * 257 + t];
  const float* e = emb + (size_t)tok * 512;
  unsigned short* o = X + (size_t)row * 512;
  for (int i = threadIdx.x; i < 512; i += blockDim.x) o[i] = f2bf(e[i]);
}

// h_buf[b][0][:] = bf16(initial_state)  (state "after step -1")
__global__ void k_init_h0(const float* __restrict__ init, unsigned short* __restrict__ hbuf){
  int i = blockIdx.x * 256 + threadIdx.x;   // 16*1024
  int b = i >> 10, u = i & 1023;
  hbuf[(size_t)(b * 257) * 1024 + u] = f2bf(init[u]);
}

// dst(C,R) bf16 = transpose(src(R,C) f32); R,C multiples of 64
__global__ __launch_bounds__(256) void k_transpose(
    const float* __restrict__ src, unsigned short* __restrict__ dst, int R, int C)
{
  __shared__ float tile[64][65];
  int c0 = blockIdx.x << 6, r0 = blockIdx.y << 6;
  int tid = threadIdx.x;
  for (int i = 0; i < 16; i++){
    int e = (i << 8) + tid; int r = e >> 6, c = e & 63;
    tile[r][c] = src[(size_t)(r0 + r) * C + c0 + c];
  }
  __syncthreads();
  for (int i = 0; i < 16; i++){
    int e = (i << 8) + tid; int rr = e >> 6, cc = e & 63;
    dst[(size_t)(c0 + rr) * R + r0 + cc] = f2bf(tile[cc][rr]);
  }
}

// guard fallback: deterministic, touches only out[0]
__global__ void k_guard(float* __restrict__ out){ if (threadIdx.x == 0) out[0] = 0.f; }

// ---------------- generic 128x128 bf16 MFMA GEMM (m97-style) ----------------
// mode 0 (ZI):  C[m*1024+n]   = A(X,512-stride) @ B(Wit)  + b0[n]+b1[n]
// mode 1 (PRE): C[Zrow*1024 + 256J + n] += h_buf-rows @ B(Wt block-J rows)
// mode 2 (D):   C[m*32000+n]  = h_buf-rows @ B(Wot)
__global__ __launch_bounds__(256) void k_gemm(
    const unsigned short* __restrict__ A, const unsigned short* __restrict__ B,
    float* __restrict__ C, const float* __restrict__ b0, const float* __restrict__ b1,
    int K, int nTiles, int mode, int J, int ldb)
{
  __shared__ unsigned short aT[128 * 32];
  __shared__ unsigned short bT[128 * 32];
  int bid = blockIdx.x;
  // mode 2: mt-fastest order -> concurrent blocks share few B-tiles (L2/L3-resident)
  // and the whole A (8.4 MB); B fetched from HBM once instead of 32x.
  int mt, nt;
  if (mode == 2){ mt = bid & 31; nt = bid >> 5; }
  else          { mt = bid / nTiles; nt = bid % nTiles; }
  int m0 = mt << 7, n0 = nt << 7;
  int tid = threadIdx.x;
  int lane = tid & 63, wave = tid >> 6;
  int wm = wave >> 1, wn = wave & 1;
  int wbase = tid & ~63;

  // staging addresses: chunk e = i*256+tid covers LDS bytes e*16 -> row e>>2, k-chunk (e&3)*8
  const unsigned short* arow[2];
  int kc[2];
  for (int i = 0; i < 2; i++){
    int e = (i << 8) + tid;
    int r = m0 + (e >> 2);
    kc[i] = (e & 3) << 3;
    const unsigned short* p;
    if (mode == 0)      p = A + (size_t)r * 512;
    else if (mode == 1){ int nA = 256 >> J; int bb = r >> (8 - J); int a = r & (nA - 1);
                         p = A + (size_t)(bb * 257 + (a << J)) * 1024; }
    else               { int bb = r >> 8; int t = r & 255;
                         p = A + (size_t)(bb * 257 + t + 1) * 1024; }
    arow[i] = p;
  }
  const unsigned short* brow[2];
  for (int i = 0; i < 2; i++){
    int e = (i << 8) + tid;
    brow[i] = B + (size_t)(n0 + (e >> 2)) * ldb + ((e & 3) << 3);
  }

  f32x4 acc[4][4] = {};

  int kT = K >> 5;
  for (int kt = 0; kt < kT; kt++){
    int k0 = kt << 5;
    __syncthreads();
    for (int i = 0; i < 2; i++)
      gload16(arow[i] + k0 + kc[i], &aT[((i << 8) + wbase) << 3]);
    for (int i = 0; i < 2; i++)
      gload16(brow[i] + k0, &bT[((i << 8) + wbase) << 3]);
    __syncthreads();
    short8 af[4], bf[4];
#pragma unroll
    for (int i = 0; i < 4; i++)
      af[i] = *(const short8*)&aT[((wm << 6) + (i << 4) + (lane & 15)) * 32 + ((lane >> 4) << 3)];
#pragma unroll
    for (int j = 0; j < 4; j++)
      bf[j] = *(const short8*)&bT[((wn << 6) + (j << 4) + (lane & 15)) * 32 + ((lane >> 4) << 3)];
#pragma unroll
    for (int i = 0; i < 4; i++)
#pragma unroll
      for (int j = 0; j < 4; j++)
        acc[i][j] = __builtin_amdgcn_mfma_f32_16x16x32_bf16(af[i], bf[j], acc[i][j], 0, 0, 0);
  }

#pragma unroll
  for (int i = 0; i < 4; i++)
#pragma unroll
    for (int j = 0; j < 4; j++)
#pragma unroll
      for (int r = 0; r < 4; r++){
        int mg = m0 + (wm << 6) + (i << 4) + ((lane >> 4) << 2) + r;
        int ng = n0 + (wn << 6) + (j << 4) + (lane & 15);
        float v = acc[i][j][r];
        if (mode == 0){
          C[(size_t)mg * 1024 + ng] = v + b0[ng] + b1[ng];
        } else if (mode == 1){
          int nA = 256 >> J; int bb = mg >> (8 - J); int a = mg & (nA - 1);
          C[(size_t)(bb * 256 + (a << J)) * 1024 + (J << 8) + ng] += v;
        } else {
          C[(size_t)mg * 32000 + ng] = v;
        }
      }
}

// ---------------- sequential self-recurrent chain for clock-block J ----------------
// one workgroup, 512 threads (8 waves); W_JJ^T held in registers (16 frags/lane);
// h (16 batches x 256 units, bf16) in LDS; per active step:
//   h = tanh(Z[t] (incl. lower-block contrib) + h_prev @ W_JJ)
// then broadcast h into h_buf rows t+1 .. t+p.
// Z is DOUBLE-BUFFERED: step t+p's loads issue before step t's MFMAs, so the
// L3/HBM latency (~500-900cy) hides under a full step instead of stalling tanh.
__global__ __launch_bounds__(512) void k_chain(
    const float* __restrict__ Z, unsigned short* __restrict__ hbuf,
    const unsigned short* __restrict__ Wt, const float* __restrict__ init, int J)
{
  __shared__ unsigned short h[16][264];   // +8 pad: conflict-free b128 frag reads
  const int p = 1 << J;
  int tid = threadIdx.x, lane = tid & 63, wave = tid >> 6;

  for (int i = tid; i < 4096; i += 512){
    int b = i >> 8, c = i & 255;
    h[b][c] = f2bf(init[(J << 8) + c]);
  }

  short8 wf[2][8];   // B frags: B[k][n] = Wt[256J+n][256J+k]
#pragma unroll
  for (int nt = 0; nt < 2; nt++){
    int ncol = (wave << 5) + (nt << 4) + (lane & 15);
    const unsigned short* wr = Wt + (size_t)((J << 8) + ncol) * 1024 + (J << 8) + ((lane >> 4) << 3);
#pragma unroll
    for (int ks = 0; ks < 8; ks++)
      wf[nt][ks] = *(const short8*)(wr + (ks << 5));
  }

  // Z prologue: load step 0
  float zcur[2][4];
#pragma unroll
  for (int nt = 0; nt < 2; nt++)
#pragma unroll
    for (int r = 0; r < 4; r++){
      int b = ((lane >> 4) << 2) + r;
      int c = (wave << 5) + (nt << 4) + (lane & 15);
      zcur[nt][r] = Z[(size_t)(b << 8) * 1024 + (J << 8) + c];
    }
  __syncthreads();

  for (int t = 0; t < 256; t += p){
    short8 af[8];
#pragma unroll
    for (int ks = 0; ks < 8; ks++)
      af[ks] = *(const short8*)&h[lane & 15][(ks << 5) + ((lane >> 4) << 3)];

    float znext[2][4];              // prefetch NEXT step's Z (wait lands at loop bottom)
    int tn = (t + p) & 255;         // last-iter wrap: harmless dummy load
#pragma unroll
    for (int nt = 0; nt < 2; nt++)
#pragma unroll
      for (int r = 0; r < 4; r++){
        int b = ((lane >> 4) << 2) + r;
        int c = (wave << 5) + (nt << 4) + (lane & 15);
        znext[nt][r] = Z[(size_t)((b << 8) + tn) * 1024 + (J << 8) + c];
      }

    f32x4 acc[2] = {};
#pragma unroll
    for (int nt = 0; nt < 2; nt++)
#pragma unroll
      for (int ks = 0; ks < 8; ks++)
        acc[nt] = __builtin_amdgcn_mfma_f32_16x16x32_bf16(af[ks], wf[nt][ks], acc[nt], 0, 0, 0);

    __syncthreads();                // all waves done reading h
#pragma unroll
    for (int nt = 0; nt < 2; nt++)
#pragma unroll
      for (int r = 0; r < 4; r++){
        int b = ((lane >> 4) << 2) + r;
        int c = (wave << 5) + (nt << 4) + (lane & 15);
        h[b][c] = f2bf(tanh_fast(acc[nt][r] + zcur[nt][r]));
      }
    __syncthreads();                // h complete before reads/copy

    for (int q = 0; q < p; q++){    // broadcast held state
      int ti = t + q + 1;
#pragma unroll
      for (int i = 0; i < 4; i++){
        int d = tid + (i << 9);     // 0..2047 dwords (16 rows * 128)
        int b = d >> 7, cp = d & 127;
        *(unsigned int*)(hbuf + (size_t)(b * 257 + ti) * 1024 + (J << 8) + (cp << 1)) =
            *(const unsigned int*)&h[b][cp << 1];
      }
    }

#pragma unroll
    for (int nt = 0; nt < 2; nt++)
#pragma unroll
      for (int r = 0; r < 4; r++)
        zcur[nt][r] = znext[nt][r]; // vmcnt wait here, ~1 full step after issue
  }
}

// ---------------- loss: one-pass online logsumexp per row + masked target gather ----------------
// float4 main loop (head/tail peel for the +4B-misaligned logits base) with 4
// independent online-LSE accumulators -> dependency chain depth 125 -> ~31.
__global__ __launch_bounds__(256) void k_loss_rows(
    const float* __restrict__ L, const int* __restrict__ x,
    const int* __restrict__ xsl, float* __restrict__ lacc)
{
  int row = blockIdx.x;             // b*256+t
  int b = row >> 8, t = row & 255;
  const float* Lr = L + (size_t)row * 32000;
  int tid = threadIdx.x, lane = tid & 63, wave = tid >> 6;

  float m4[4] = {-3.0e38f, -3.0e38f, -3.0e38f, -3.0e38f};
  float s4[4] = {0.f, 0.f, 0.f, 0.f};

  // head: floats 0..2 (so Lr+3 is 16B-aligned); tail: float 31999
  if (tid < 3){
    float v = Lr[tid];
    float mn = fmaxf(m4[0], v);
    s4[0] = s4[0] * __builtin_amdgcn_exp2f((m4[0] - mn) * LOG2E)
          + __builtin_amdgcn_exp2f((v - mn) * LOG2E);
    m4[0] = mn;
  }
  if (tid == 3){
    float v = Lr[31999];
    float mn = fmaxf(m4[1], v);
    s4[1] = s4[1] * __builtin_amdgcn_exp2f((m4[1] - mn) * LOG2E)
          + __builtin_amdgcn_exp2f((v - mn) * LOG2E);
    m4[1] = mn;
  }

  const float4* L4 = (const float4*)(Lr + 3);   // 7999 vec4 = floats 3..31998
  for (int i = tid; i < 7999; i += 256){
    float4 v = L4[i];
    float vj[4] = {v.x, v.y, v.z, v.w};
#pragma unroll
    for (int j = 0; j < 4; j++){
      float mn = fmaxf(m4[j], vj[j]);
      s4[j] = s4[j] * __builtin_amdgcn_exp2f((m4[j] - mn) * LOG2E)
            + __builtin_amdgcn_exp2f((vj[j] - mn) * LOG2E);
      m4[j] = mn;
    }
  }

  // merge the 4 independent chains
  float m = fmaxf(fmaxf(m4[0], m4[1]), fmaxf(m4[2], m4[3]));
  float s = 0.f;
#pragma unroll
  for (int j = 0; j < 4; j++)
    s += s4[j] * __builtin_amdgcn_exp2f((m4[j] - m) * LOG2E);

  __shared__ float smax[4], ssum[4];
  float wm_ = m;
  for (int off = 32; off >= 1; off >>= 1) wm_ = fmaxf(wm_, __shfl_xor(wm_, off));
  if (lane == 0) smax[wave] = wm_;
  __syncthreads();
  float M = fmaxf(fmaxf(smax[0], smax[1]), fmaxf(smax[2], smax[3]));
  float sc = s * __builtin_amdgcn_exp2f((m - M) * LOG2E);
  for (int off = 32; off >= 1; off >>= 1) sc += __shfl_xor(sc, off);
  if (lane == 0) ssum[wave] = sc;
  __syncthreads();
  if (tid == 0){
    float S = ssum[0] + ssum[1] + ssum[2] + ssum[3];
    float lse = M + __builtin_amdgcn_logf(S) * 0.6931471805599453f;
    int y = x[b * 257 + t + 1];
    if (t < xsl[b] - 1) atomicAdd(lacc, Lr[y] - lse);
  }
}

__global__ void k_final(const float* __restrict__ lacc, const int* __restrict__ xsl,
                        float* __restrict__ out){
  if (threadIdx.x == 0){
    int ss = 0;
    for (int b = 0; b < 16; b++) ss += xsl[b] - 1;
    out[0] = -lacc[0] / (float)ss;
  }
}

// ---------------- launch ----------------
extern "C" void kernel_launch(void* const* d_in, const int* in_sizes, int n_in,
                              void* d_out, int out_size, void* d_ws, size_t ws_size,
                              hipStream_t stream)
{
  const int*   x   = (const int*)d_in[0];
  const int*   xsl = (const int*)d_in[1];
  const float* Wi  = (const float*)d_in[2];
  const float* Wh  = (const float*)d_in[3];
  const float* Wo  = (const float*)d_in[4];
  const float* bi  = (const float*)d_in[5];
  const float* bh  = (const float*)d_in[6];
  const float* ini = (const float*)d_in[7];
  const float* emb = (const float*)d_in[8];
  float* out = (float*)d_out;

  // workspace layout (bytes)
  const size_t WS_NEED = 98074628;
  if (ws_size < WS_NEED){           // refuse to scribble OOB: clean fail, not a crash
    k_guard<<<1, 64, 0, stream>>>(out);
    return;
  }

  char* ws = (char*)d_ws;
  float*          Z    = (float*)(ws + 0);                   // 4096*1024 f32   = 16777216
  unsigned short* hbuf = (unsigned short*)(ws + 16777216);   // 16*257*1024 bf16 = 8421376
  unsigned short* Wt   = (unsigned short*)(ws + 25198592);   // 1024*1024 bf16   = 2097152
  unsigned short* Wit  = (unsigned short*)(ws + 27295744);   // 1024*512 bf16    = 1048576
  unsigned short* X    = (unsigned short*)(ws + 28344320);   // 4096*512 bf16    = 4194304
  unsigned short* Wot  = (unsigned short*)(ws + 32538624);   // 32000*1024 bf16  = 65536000
  float*          lacc = (float*)(ws + 98074624);

  hipMemsetAsync(lacc, 0, 4, stream);

  k_gather_x<<<4096, 128, 0, stream>>>(x, emb, X);
  k_init_h0<<<64, 256, 0, stream>>>(ini, hbuf);
  k_transpose<<<dim3(1024 / 64, 512 / 64), 256, 0, stream>>>(Wi, Wit, 512, 1024);
  k_transpose<<<dim3(1024 / 64, 1024 / 64), 256, 0, stream>>>(Wh, Wt, 1024, 1024);
  k_transpose<<<dim3(32000 / 64, 1024 / 64), 256, 0, stream>>>(Wo, Wot, 1024, 32000);

  // Z = X @ Wi^T + (bi+bh)   : M=4096 N=1024 K=512
  k_gemm<<<(4096 / 128) * (1024 / 128), 256, 0, stream>>>(X, Wit, Z, bi, bh, 512, 8, 0, 0, 512);

  // clockwork phases
  k_chain<<<1, 512, 0, stream>>>(Z, hbuf, Wt, ini, 0);
  for (int j = 1; j <= 3; j++){
    int nA = 256 >> j;
    int grid = ((16 * nA) / 128) * 2;    // M/128 * N-tiles(2)
    k_gemm<<<grid, 256, 0, stream>>>(hbuf, Wt + (size_t)(256 * j) * 1024, Z,
                                     nullptr, nullptr, 256 * j, 2, 1, j, 1024);
    k_chain<<<1, 512, 0, stream>>>(Z, hbuf, Wt, ini, j);
  }

  // logits = h @ Wo : M=4096 N=32000 K=1024  -> d_out+1
  k_gemm<<<(4096 / 128) * (32000 / 128), 256, 0, stream>>>(hbuf, Wot, out + 1,
                                   nullptr, nullptr, 1024, 250, 2, 0, 1024);

  k_loss_rows<<<4096, 256, 0, stream>>>(out + 1, x, xsl, lacc);
  k_final<<<1, 64, 0, stream>>>(lacc, xsl, out);
}